// Round 1
// baseline (304.744 us; speedup 1.0000x reference)
//
#include <hip/hip_runtime.h>
#include <math.h>

// Problem constants (match reference)
#define BATCH 8192
#define DIM   1024
#define GRP   8
#define NPART 256                         // number of partial sums in ws
constexpr float EPS   = 1e-12f;
constexpr float INV_N = 1.0f / (float(BATCH) * float(DIM)); // 1 / 8388608

// ---------------------------------------------------------------------------
// Kernel A: partial sums of xf -> ws[0..255]. 256 blocks x 1024 threads,
// each thread sums 8 float4s (fully unrolled), block reduce, one store.
// All 256 slots are overwritten, so no zero-init of ws is needed.
// ---------------------------------------------------------------------------
__global__ __launch_bounds__(1024)
void partial_sum_kernel(const float* __restrict__ xf,
                        float* __restrict__ ws) {
    const int tid = threadIdx.x;
    const int gid = blockIdx.x * 1024 + tid;           // 0 .. 262143
    const float4* x4 = reinterpret_cast<const float4*>(xf);
    // total float4 = 2097152 ; stride between a thread's loads = 262144
    float s = 0.0f;
    #pragma unroll
    for (int i = 0; i < 8; ++i) {
        float4 v = x4[gid + i * 262144];
        s += (v.x + v.y) + (v.z + v.w);
    }
    #pragma unroll
    for (int off = 32; off > 0; off >>= 1)
        s += __shfl_down(s, off, 64);

    __shared__ float sm[16];                           // 1024 threads = 16 waves
    const int lane = tid & 63;
    const int wave = tid >> 6;
    if (lane == 0) sm[wave] = s;
    __syncthreads();
    if (tid == 0) {
        float t = 0.0f;
        #pragma unroll
        for (int w = 0; w < 16; ++w) t += sm[w];
        ws[blockIdx.x] = t;
    }
}

// ---------------------------------------------------------------------------
// Kernel B (restructured): one 64-lane WAVE per row. No __syncthreads, no LDS.
// Each wave: load its 1024-float row (4 coalesced float4 per lane), reduce the
// 256 partial sums itself (4 loads + butterfly shfl_xor -> mean in ALL lanes),
// relu(x-mean), butterfly sum-of-squares, scale by sigmoid(wp)/norm, then
// stream 8 tiled copies with plain coalesced float4 stores.
// Grid = 2048 blocks x 256 threads = 8192 waves = 32 waves/CU: the whole grid
// is co-resident, so prologue latency is paid once and store issue is
// continuous (the fill kernel proves plain stores reach ~6.5 TB/s here).
// ---------------------------------------------------------------------------
__device__ __forceinline__ float4 relu_sub(float4 v, float m) {
    v.x = fmaxf(v.x - m, 0.0f);
    v.y = fmaxf(v.y - m, 0.0f);
    v.z = fmaxf(v.z - m, 0.0f);
    v.w = fmaxf(v.w - m, 0.0f);
    return v;
}
__device__ __forceinline__ float ssq4(float4 v) {
    return (v.x * v.x + v.y * v.y) + (v.z * v.z + v.w * v.w);
}
__device__ __forceinline__ float4 mul4(float4 v, float s) {
    v.x *= s; v.y *= s; v.z *= s; v.w *= s;
    return v;
}

__global__ __launch_bounds__(256)
void norm_tile_kernel(const float* __restrict__ xf,
                      const float* __restrict__ wp,
                      const float* __restrict__ ws,
                      float* __restrict__ out) {
    const int tid  = threadIdx.x;                      // 0..255
    const int lane = tid & 63;
    const int row  = (blockIdx.x << 2) | (tid >> 6);   // one row per wave

    // Issue the row loads first so they overlap the partial-sum reduction.
    const float4* xr = reinterpret_cast<const float4*>(xf + (size_t)row * DIM);
    float4 v0 = xr[lane];
    float4 v1 = xr[lane + 64];
    float4 v2 = xr[lane + 128];
    float4 v3 = xr[lane + 192];

    // Reduce the 256 partial sums -> global mean, butterfly so ALL lanes have it.
    float p = (ws[lane] + ws[lane + 64]) + (ws[lane + 128] + ws[lane + 192]);
    #pragma unroll
    for (int off = 32; off > 0; off >>= 1)
        p += __shfl_xor(p, off, 64);
    const float mean = p * INV_N;

    // ReLU(x - mean) and row sum of squares (butterfly -> all lanes).
    v0 = relu_sub(v0, mean);
    v1 = relu_sub(v1, mean);
    v2 = relu_sub(v2, mean);
    v3 = relu_sub(v3, mean);

    float s = (ssq4(v0) + ssq4(v1)) + (ssq4(v2) + ssq4(v3));
    #pragma unroll
    for (int off = 32; off > 0; off >>= 1)
        s += __shfl_xor(s, off, 64);

    const float sig   = 1.0f / (1.0f + expf(-wp[0]));
    const float scale = sig / fmaxf(sqrtf(s), EPS);

    v0 = mul4(v0, scale);
    v1 = mul4(v1, scale);
    v2 = mul4(v2, scale);
    v3 = mul4(v3, scale);

    // 8 tiled copies, plain coalesced float4 stores (1 KB per wave per instr).
    float4* orow = reinterpret_cast<float4*>(out + (size_t)row * (GRP * DIM));
    #pragma unroll
    for (int g = 0; g < GRP; ++g) {
        const int b = g * (DIM / 4);
        orow[b + lane]       = v0;
        orow[b + lane + 64]  = v1;
        orow[b + lane + 128] = v2;
        orow[b + lane + 192] = v3;
    }
}

// ---------------------------------------------------------------------------
extern "C" void kernel_launch(void* const* d_in, const int* in_sizes, int n_in,
                              void* d_out, int out_size, void* d_ws, size_t ws_size,
                              hipStream_t stream) {
    const float* xf = (const float*)d_in[0];   // [8192,1024] fp32
    const float* wp = (const float*)d_in[1];   // [1] fp32
    // d_in[2] is W_tile = kron(ones(1,8), eye(1024)) -> output is 8 tiled
    // copies of the normalized row; no GEMM needed.
    float* out = (float*)d_out;                // [8192, 8192] fp32
    float* ws  = (float*)d_ws;                 // ws[0..255] partial sums

    partial_sum_kernel<<<NPART, 1024, 0, stream>>>(xf, ws);
    norm_tile_kernel<<<BATCH / 4, 256, 0, stream>>>(xf, wp, ws, out);
}